// Round 3
// baseline (4257.226 us; speedup 1.0000x reference)
//
#include <hip/hip_runtime.h>
#include <hip/hip_cooperative_groups.h>
#include <math.h>

namespace cg = cooperative_groups;

#define NB 4
#define P 2048
#define DF 64
#define EPS 0.1f
#define INV_EPS 10.0f
#define MAX_ITER 50
#define NBLK 256   // 1 block per CU (cooperative)
#define TPB 512    // 8 waves
#define BPB 64     // blocks per batch
#define RPB 32     // rows per block (4 per wave)

typedef float vfloat4 __attribute__((ext_vector_type(4)));  // native vec for nt-store

struct BuildMem { float xs[RPB * DF]; float ys[32 * 260]; };  // 8KB + 33.3KB
struct CombMem  { float m[4][P]; float s[4][P]; };            // 64KB
union SMem { BuildMem b; CombMem c; };

// ---------------------------------------------------------------------------
// Persistent cooperative kernel: build C (+reg-resident scaled copy),
// 50 Sinkhorn iterations entirely from registers, pi/cost epilogue.
// Lane layout: wave w owns rows i0+4w..+3; lane l holds cols 256k+4l+e
// (k=0..7, e=0..3) of each of its 4 rows -> creg[4][32].
// ---------------------------------------------------------------------------
__global__ __launch_bounds__(TPB, 2) void sinkhorn_all(
    const float* __restrict__ x, const float* __restrict__ y,
    float* __restrict__ Cout, float* __restrict__ pi,
    float* __restrict__ cost, float2* __restrict__ part,
    float* __restrict__ Vg, float log_mu) {
  __shared__ SMem sm;
  const int t = threadIdx.x;
  const int w = t >> 6;
  const int l = t & 63;
  const int b = blockIdx.x;
  const int n = b >> 6;    // batch
  const int rb = b & 63;   // block within batch
  const int i0 = rb * RPB;
  const size_t xyb = (size_t)n * P * DF;
  const size_t cb = (size_t)n * P * P;

  float creg[4][32];  // scaled cost C*INV_EPS for this lane's 4 rows x 32 cols

  // ---------------- build phase ----------------
  {
    const int rr = t >> 4, d4 = (t & 15) * 4;
    float4 xv = *(const float4*)(x + xyb + (size_t)(i0 + rr) * DF + d4);
    sm.b.xs[rr * DF + d4 + 0] = xv.x;
    sm.b.xs[rr * DF + d4 + 1] = xv.y;
    sm.b.xs[rr * DF + d4 + 2] = xv.z;
    sm.b.xs[rr * DF + d4 + 3] = xv.w;
  }
  const int cl = t >> 1;         // y-row within 256-col chunk
  const int db = (t & 1) * 16;   // d-offset within 32-d half
#pragma unroll
  for (int k = 0; k < 8; ++k) {
    float acc[4][4];
#pragma unroll
    for (int r = 0; r < 4; ++r) acc[r][0] = acc[r][1] = acc[r][2] = acc[r][3] = 0.f;
#pragma unroll
    for (int h = 0; h < 2; ++h) {
      __syncthreads();  // protect previous ys tile use (also covers xs on first pass)
      {
        const float* yp = y + xyb + (size_t)(256 * k + cl) * DF + 32 * h + db;
        float4 q0 = *(const float4*)(yp + 0);
        float4 q1 = *(const float4*)(yp + 4);
        float4 q2 = *(const float4*)(yp + 8);
        float4 q3 = *(const float4*)(yp + 12);
        float* ys = sm.b.ys;
        ys[(db + 0) * 260 + cl] = q0.x;  ys[(db + 1) * 260 + cl] = q0.y;
        ys[(db + 2) * 260 + cl] = q0.z;  ys[(db + 3) * 260 + cl] = q0.w;
        ys[(db + 4) * 260 + cl] = q1.x;  ys[(db + 5) * 260 + cl] = q1.y;
        ys[(db + 6) * 260 + cl] = q1.z;  ys[(db + 7) * 260 + cl] = q1.w;
        ys[(db + 8) * 260 + cl] = q2.x;  ys[(db + 9) * 260 + cl] = q2.y;
        ys[(db + 10) * 260 + cl] = q2.z; ys[(db + 11) * 260 + cl] = q2.w;
        ys[(db + 12) * 260 + cl] = q3.x; ys[(db + 13) * 260 + cl] = q3.y;
        ys[(db + 14) * 260 + cl] = q3.z; ys[(db + 15) * 260 + cl] = q3.w;
      }
      __syncthreads();
#pragma unroll 8
      for (int dd = 0; dd < 32; ++dd) {
        float4 y4 = *(const float4*)&sm.b.ys[dd * 260 + 4 * l];
#pragma unroll
        for (int r = 0; r < 4; ++r) {
          float xv = sm.b.xs[(w * 4 + r) * DF + 32 * h + dd];  // wave-uniform broadcast
          float d0 = xv - y4.x; acc[r][0] = fmaf(d0, d0, acc[r][0]);
          float d1 = xv - y4.y; acc[r][1] = fmaf(d1, d1, acc[r][1]);
          float d2 = xv - y4.z; acc[r][2] = fmaf(d2, d2, acc[r][2]);
          float d3 = xv - y4.w; acc[r][3] = fmaf(d3, d3, acc[r][3]);
        }
      }
    }
#pragma unroll
    for (int r = 0; r < 4; ++r) {
      vfloat4 c4 = {acc[r][0], acc[r][1], acc[r][2], acc[r][3]};
      __builtin_nontemporal_store(c4,
          (vfloat4*)(Cout + cb + (size_t)(i0 + 4 * w + r) * P + 256 * k + 4 * l));
      creg[r][4 * k + 0] = acc[r][0] * INV_EPS;
      creg[r][4 * k + 1] = acc[r][1] * INV_EPS;
      creg[r][4 * k + 2] = acc[r][2] * INV_EPS;
      creg[r][4 * k + 3] = acc[r][3] * INV_EPS;
    }
  }
  __syncthreads();  // build->comb LDS union hazard

  // ---------------- 50 Sinkhorn iterations (scaled log domain) ----------------
  cg::grid_group grid = cg::this_grid();
  float U[4];
#pragma unroll 1
  for (int it = 0; it < MAX_ITER; ++it) {
    // u-update: wave-local row LSE.  U_i = log_mu - LSE_j(V_j - Cs_ij)
    float vreg[32];
#pragma unroll
    for (int k = 0; k < 8; ++k) {
      float4 vv = *(const float4*)(Vg + n * P + 256 * k + 4 * l);
      vreg[4 * k + 0] = vv.x; vreg[4 * k + 1] = vv.y;
      vreg[4 * k + 2] = vv.z; vreg[4 * k + 3] = vv.w;
    }
#pragma unroll
    for (int r = 0; r < 4; ++r) {
      float arg[32];
      float m = -3.4e38f;
#pragma unroll
      for (int i = 0; i < 32; ++i) {
        arg[i] = vreg[i] - creg[r][i];
        m = fmaxf(m, arg[i]);
      }
#pragma unroll
      for (int off = 32; off; off >>= 1) m = fmaxf(m, __shfl_xor(m, off));
      float s = 0.f;
#pragma unroll
      for (int i = 0; i < 32; ++i) s += __expf(arg[i] - m);
#pragma unroll
      for (int off = 32; off; off >>= 1) s += __shfl_xor(s, off);
      U[r] = log_mu - (m + __logf(s));
    }
    // v-update partials over this wave's 4 rows (per column)
    float pm[32], ps[32];
#pragma unroll
    for (int i = 0; i < 32; ++i) {
      float a0 = U[0] - creg[0][i];
      float a1 = U[1] - creg[1][i];
      float a2 = U[2] - creg[2][i];
      float a3 = U[3] - creg[3][i];
      float m = fmaxf(fmaxf(a0, a1), fmaxf(a2, a3));
      pm[i] = m;
      ps[i] = __expf(a0 - m) + __expf(a1 - m) + __expf(a2 - m) + __expf(a3 - m);
    }
    // combine 8 waves -> 4 -> 1 via LDS (swizzled idx = 256k + 64e + l: conflict-free)
    if (w >= 4) {
#pragma unroll
      for (int i = 0; i < 32; ++i) {
        int idx = 256 * (i >> 2) + 64 * (i & 3) + l;
        sm.c.m[w - 4][idx] = pm[i];
        sm.c.s[w - 4][idx] = ps[i];
      }
    }
    __syncthreads();
    if (w < 4) {
#pragma unroll
      for (int i = 0; i < 32; ++i) {
        int idx = 256 * (i >> 2) + 64 * (i & 3) + l;
        float om = sm.c.m[w][idx], os = sm.c.s[w][idx];
        float M = fmaxf(pm[i], om);
        float S = ps[i] * __expf(pm[i] - M) + os * __expf(om - M);
        sm.c.m[w][idx] = M;
        sm.c.s[w][idx] = S;
      }
    }
    __syncthreads();
#pragma unroll
    for (int q = 0; q < 4; ++q) {
      int idx = t + 512 * q;  // storage order -> coalesced global write
      float m0 = sm.c.m[0][idx], m1 = sm.c.m[1][idx];
      float m2 = sm.c.m[2][idx], m3 = sm.c.m[3][idx];
      float s0 = sm.c.s[0][idx], s1 = sm.c.s[1][idx];
      float s2 = sm.c.s[2][idx], s3 = sm.c.s[3][idx];
      float M = fmaxf(fmaxf(m0, m1), fmaxf(m2, m3));
      float S = s0 * __expf(m0 - M) + s1 * __expf(m1 - M)
              + s2 * __expf(m2 - M) + s3 * __expf(m3 - M);
      part[(size_t)(n * BPB + rb) * P + idx] = make_float2(M, S);
    }
    grid.sync();
    // reduce 64 block-partials per column -> V (block b owns cols b*32..+32)
    if (t < 32) {
      int g = b * 32 + t;
      int n2 = g >> 11, j = g & 2047;
      int pos = (j & ~255) + 64 * (j & 3) + ((j >> 2) & 63);  // un-swizzle
      float M = -3.4e38f, S = 0.f;
#pragma unroll 8
      for (int kk = 0; kk < BPB; ++kk) {
        float2 pp = part[(size_t)(n2 * BPB + kk) * P + pos];
        float Mn = fmaxf(M, pp.x);
        S = S * __expf(M - Mn) + pp.y * __expf(pp.x - Mn);
        M = Mn;
      }
      Vg[g] = log_mu - (M + __logf(S));
    }
    grid.sync();
  }

  // ---------------- epilogue: pi and cost ----------------
  float vreg2[32];
#pragma unroll
  for (int k = 0; k < 8; ++k) {
    float4 vv = *(const float4*)(Vg + n * P + 256 * k + 4 * l);
    vreg2[4 * k + 0] = vv.x; vreg2[4 * k + 1] = vv.y;
    vreg2[4 * k + 2] = vv.z; vreg2[4 * k + 3] = vv.w;
  }
  grid.sync();  // Vg/part live inside pi region: all reads done before overwrite
  float csum = 0.f;
#pragma unroll
  for (int r = 0; r < 4; ++r) {
    const size_t rowb = cb + (size_t)(i0 + 4 * w + r) * P;
#pragma unroll
    for (int k = 0; k < 8; ++k) {
      vfloat4 p4;
      p4.x = __expf(U[r] + vreg2[4 * k + 0] - creg[r][4 * k + 0]);
      p4.y = __expf(U[r] + vreg2[4 * k + 1] - creg[r][4 * k + 1]);
      p4.z = __expf(U[r] + vreg2[4 * k + 2] - creg[r][4 * k + 2]);
      p4.w = __expf(U[r] + vreg2[4 * k + 3] - creg[r][4 * k + 3]);
      csum += p4.x * creg[r][4 * k + 0] + p4.y * creg[r][4 * k + 1]
            + p4.z * creg[r][4 * k + 2] + p4.w * creg[r][4 * k + 3];
      __builtin_nontemporal_store(p4, (vfloat4*)(pi + rowb + 256 * k + 4 * l));
    }
  }
  csum *= EPS;  // creg is C*INV_EPS, so sum(pi*creg)*EPS = sum(pi*C)
#pragma unroll
  for (int off = 32; off; off >>= 1) csum += __shfl_xor(csum, off);
  if (l == 0) atomicAdd(cost + n, csum);
}

// ===========================================================================
// Fallback path (round-1 kernels, known-good) in case cooperative launch fails
// ===========================================================================
__global__ __launch_bounds__(256) void build_c(const float* __restrict__ x,
                                               const float* __restrict__ y,
                                               float* __restrict__ C,
                                               float* __restrict__ CT) {
  __shared__ float xs[DF][68];
  __shared__ float ys[DF][68];
  const int n = blockIdx.z;
  const int i0 = blockIdx.y * 64, j0 = blockIdx.x * 64;
  const int t = threadIdx.x;
  const int lr = t >> 4, c4 = (t & 15) * 4;
  const size_t xb = (size_t)n * P * DF;
  for (int rr = lr; rr < 64; rr += 16) {
    float4 xv = *(const float4*)(x + xb + (size_t)(i0 + rr) * DF + c4);
    float4 yv = *(const float4*)(y + xb + (size_t)(j0 + rr) * DF + c4);
    xs[c4 + 0][rr] = xv.x; xs[c4 + 1][rr] = xv.y;
    xs[c4 + 2][rr] = xv.z; xs[c4 + 3][rr] = xv.w;
    ys[c4 + 0][rr] = yv.x; ys[c4 + 1][rr] = yv.y;
    ys[c4 + 2][rr] = yv.z; ys[c4 + 3][rr] = yv.w;
  }
  __syncthreads();
  const int ty = t >> 4, tx = t & 15;
  float acc[4][4];
#pragma unroll
  for (int e = 0; e < 4; ++e)
#pragma unroll
    for (int f = 0; f < 4; ++f) acc[e][f] = 0.f;
#pragma unroll 4
  for (int d = 0; d < DF; ++d) {
    float4 a4 = *(const float4*)&xs[d][4 * ty];
    float4 b4 = *(const float4*)&ys[d][4 * tx];
    float av[4] = {a4.x, a4.y, a4.z, a4.w};
    float bv[4] = {b4.x, b4.y, b4.z, b4.w};
#pragma unroll
    for (int e = 0; e < 4; ++e)
#pragma unroll
      for (int f = 0; f < 4; ++f) {
        float df = av[e] - bv[f];
        acc[e][f] = fmaf(df, df, acc[e][f]);
      }
  }
  const size_t cbase = (size_t)n * P * P;
#pragma unroll
  for (int e = 0; e < 4; ++e) {
    float4 v4 = make_float4(acc[e][0], acc[e][1], acc[e][2], acc[e][3]);
    *(float4*)(C + cbase + (size_t)(i0 + 4 * ty + e) * P + (j0 + 4 * tx)) = v4;
  }
#pragma unroll
  for (int f = 0; f < 4; ++f) {
    float4 v4 = make_float4(acc[0][f], acc[1][f], acc[2][f], acc[3][f]);
    *(float4*)(CT + cbase + (size_t)(j0 + 4 * tx + f) * P + (i0 + 4 * ty)) = v4;
  }
}

__global__ __launch_bounds__(256) void lse_pass(const float* __restrict__ M,
                                                const float* __restrict__ wv_,
                                                float* __restrict__ out,
                                                float log_w) {
  __shared__ float red[8];
  const int b = blockIdx.x;
  const int n = b >> 11;
  const int t = threadIdx.x;
  const float4* row = (const float4*)(M + (size_t)b * P);
  const float4* wv = (const float4*)(wv_ + (size_t)n * P);
  float4 c0 = row[t], c1 = row[t + 256];
  float4 w0 = wv[t], w1 = wv[t + 256];
  float a[8];
  a[0] = (w0.x - c0.x) * INV_EPS; a[1] = (w0.y - c0.y) * INV_EPS;
  a[2] = (w0.z - c0.z) * INV_EPS; a[3] = (w0.w - c0.w) * INV_EPS;
  a[4] = (w1.x - c1.x) * INV_EPS; a[5] = (w1.y - c1.y) * INV_EPS;
  a[6] = (w1.z - c1.z) * INV_EPS; a[7] = (w1.w - c1.w) * INV_EPS;
  float mx = a[0];
#pragma unroll
  for (int k = 1; k < 8; ++k) mx = fmaxf(mx, a[k]);
#pragma unroll
  for (int o = 32; o > 0; o >>= 1) mx = fmaxf(mx, __shfl_xor(mx, o));
  if ((t & 63) == 0) red[t >> 6] = mx;
  __syncthreads();
  mx = fmaxf(fmaxf(red[0], red[1]), fmaxf(red[2], red[3]));
  float s = 0.f;
#pragma unroll
  for (int k = 0; k < 8; ++k) s += __expf(a[k] - mx);
#pragma unroll
  for (int o = 32; o > 0; o >>= 1) s += __shfl_xor(s, o);
  if ((t & 63) == 0) red[4 + (t >> 6)] = s;
  __syncthreads();
  if (t == 0) {
    float S = red[4] + red[5] + red[6] + red[7];
    out[b] = EPS * (log_w - (mx + __logf(S)));
  }
}

__global__ __launch_bounds__(256) void final_pass(const float* __restrict__ C,
                                                  const float* __restrict__ u,
                                                  const float* __restrict__ v,
                                                  float* __restrict__ pi,
                                                  float* __restrict__ cost) {
  __shared__ float red[4];
  const int b = blockIdx.x;
  const int n = b >> 11;
  const int t = threadIdx.x;
  const float ui = u[b];
  const float4* row = (const float4*)(C + (size_t)b * P);
  const float4* vv = (const float4*)(v + (size_t)n * P);
  float4* prow = (float4*)(pi + (size_t)b * P);
  float local = 0.f;
#pragma unroll
  for (int h = 0; h < 2; ++h) {
    float4 c = row[t + 256 * h];
    float4 vw = vv[t + 256 * h];
    float4 p;
    p.x = __expf((ui + vw.x - c.x) * INV_EPS);
    p.y = __expf((ui + vw.y - c.y) * INV_EPS);
    p.z = __expf((ui + vw.z - c.z) * INV_EPS);
    p.w = __expf((ui + vw.w - c.w) * INV_EPS);
    prow[t + 256 * h] = p;
    local += p.x * c.x + p.y * c.y + p.z * c.z + p.w * c.w;
  }
#pragma unroll
  for (int o = 32; o > 0; o >>= 1) local += __shfl_xor(local, o);
  if ((t & 63) == 0) red[t >> 6] = local;
  __syncthreads();
  if (t == 0) {
    float S = red[0] + red[1] + red[2] + red[3];
    atomicAdd(cost + n, S);
  }
}

extern "C" void kernel_launch(void* const* d_in, const int* in_sizes, int n_in,
                              void* d_out, int out_size, void* d_ws, size_t ws_size,
                              hipStream_t stream) {
  const float* x = (const float*)d_in[0];
  const float* y = (const float*)d_in[1];
  float* cost = (float*)d_out;                 // 4 floats
  float* pi = cost + 4;                        // 4*2048*2048
  float* C = pi + (size_t)NB * P * P;          // 4*2048*2048
  // scratch carved out of the pi output slot (fully overwritten by epilogue):
  float2* part = (float2*)pi;                           // 4 MB of partials
  float* Vg = pi + (size_t)NB * BPB * P * 2;            // 32 KB V vector

  (void)hipMemsetAsync(cost, 0, NB * sizeof(float), stream);
  (void)hipMemsetAsync(Vg, 0, NB * P * sizeof(float), stream);

  float lmu = logf(1.0f / (float)P + 1e-8f);  // == log_nu

  void* args[] = {(void*)&x, (void*)&y, (void*)&C, (void*)&pi,
                  (void*)&cost, (void*)&part, (void*)&Vg, (void*)&lmu};
  hipError_t err = hipLaunchCooperativeKernel((void*)sinkhorn_all, dim3(NBLK),
                                              dim3(TPB), args, 0, stream);
  if (err != hipSuccess) {
    // fallback: round-1 multi-kernel path (deterministically taken if coop fails)
    float* u = (float*)d_ws;
    float* v = u + NB * P;
    (void)hipMemsetAsync(v, 0, NB * P * sizeof(float), stream);
    float* CT = pi;
    build_c<<<dim3(32, 32, 4), 256, 0, stream>>>(x, y, C, CT);
    for (int it = 0; it < MAX_ITER; ++it) {
      lse_pass<<<NB * P, 256, 0, stream>>>(C, v, u, lmu);
      lse_pass<<<NB * P, 256, 0, stream>>>(CT, u, v, lmu);
    }
    final_pass<<<NB * P, 256, 0, stream>>>(C, u, v, pi, cost);
  }
}

// Round 4
// 2362.421 us; speedup vs baseline: 1.8021x; 1.8021x over previous
//
#include <hip/hip_runtime.h>
#include <math.h>

#define NB 4
#define P 2048
#define DF 64
#define EPS 0.1f
#define INV_EPS 10.0f
#define MAX_ITER 50
#define NBLK 256   // 1 block per CU (cooperative, co-resident)
#define TPB 512    // 8 waves
#define BPB 64     // blocks per batch
#define RPB 32     // rows per block (4 per wave)

typedef float vfloat4 __attribute__((ext_vector_type(4)));  // native vec for nt-store

struct BuildMem { float xs[RPB * DF]; float ys[32 * 260]; };  // 8KB + 33.3KB
struct CombMem  { float m[4][P]; float s[4][P]; };            // 64KB
union SMem { BuildMem b; CombMem c; };

// ---------------------------------------------------------------------------
// Custom arrive-and-wait barrier (monotonic counter, agent scope).
// grid.sync() measured ~36us on 256 blocks; this is ~2-4us for 64 blocks.
// Safe only because cooperative launch guarantees co-residency.
// ---------------------------------------------------------------------------
__device__ __forceinline__ void barrier_wait(unsigned* ctr, unsigned target, int t) {
  __syncthreads();  // drain all waves' prior stores (s_waitcnt vmcnt(0) per wave)
  if (t == 0) {
    __threadfence();  // agent-scope release (L2 writeback)
    __hip_atomic_fetch_add(ctr, 1u, __ATOMIC_RELAXED, __HIP_MEMORY_SCOPE_AGENT);
    while (__hip_atomic_load(ctr, __ATOMIC_RELAXED, __HIP_MEMORY_SCOPE_AGENT) < target)
      __builtin_amdgcn_s_sleep(1);
    __threadfence();  // agent-scope acquire (L1/L2 invalidate)
  }
  __syncthreads();
}

// ---------------------------------------------------------------------------
// Persistent cooperative kernel: build C (+reg-resident scaled copy),
// 50 Sinkhorn iterations entirely from registers, pi/cost epilogue.
// Lane layout: wave w owns rows i0+4w..+3; lane l holds cols 256k+4l+e
// (k=0..7, e=0..3) of each of its 4 rows -> creg[4][32].
// ---------------------------------------------------------------------------
__global__ __launch_bounds__(TPB, 2) void sinkhorn_all(
    const float* __restrict__ x, const float* __restrict__ y,
    float* __restrict__ Cout, float* __restrict__ pi,
    float* __restrict__ cost, float2* __restrict__ part,
    float* __restrict__ Vg, unsigned* __restrict__ cnt, float log_mu) {
  __shared__ SMem sm;
  const int t = threadIdx.x;
  const int w = t >> 6;
  const int l = t & 63;
  const int b = blockIdx.x;
  const int n = b >> 6;    // batch
  const int rb = b & 63;   // block within batch
  const int i0 = rb * RPB;
  const size_t xyb = (size_t)n * P * DF;
  const size_t cb = (size_t)n * P * P;
  unsigned* cntA = cnt + 32 * n;        // per-batch barrier A (partials ready)
  unsigned* cntB = cnt + 128 + 32 * n;  // per-batch barrier B (V ready)
  unsigned* cntC = cnt + 240;           // global barrier (epilogue)

  float creg[4][32];  // scaled cost C*INV_EPS for this lane's 4 rows x 32 cols

  // ---------------- build phase ----------------
  {
    const int rr = t >> 4, d4 = (t & 15) * 4;
    float4 xv = *(const float4*)(x + xyb + (size_t)(i0 + rr) * DF + d4);
    sm.b.xs[rr * DF + d4 + 0] = xv.x;
    sm.b.xs[rr * DF + d4 + 1] = xv.y;
    sm.b.xs[rr * DF + d4 + 2] = xv.z;
    sm.b.xs[rr * DF + d4 + 3] = xv.w;
  }
  const int cl = t >> 1;         // y-row within 256-col chunk
  const int db = (t & 1) * 16;   // d-offset within 32-d half
#pragma unroll
  for (int k = 0; k < 8; ++k) {
    float acc[4][4];
#pragma unroll
    for (int r = 0; r < 4; ++r) acc[r][0] = acc[r][1] = acc[r][2] = acc[r][3] = 0.f;
#pragma unroll
    for (int h = 0; h < 2; ++h) {
      __syncthreads();  // protect previous ys tile use (also covers xs on first pass)
      {
        const float* yp = y + xyb + (size_t)(256 * k + cl) * DF + 32 * h + db;
        float4 q0 = *(const float4*)(yp + 0);
        float4 q1 = *(const float4*)(yp + 4);
        float4 q2 = *(const float4*)(yp + 8);
        float4 q3 = *(const float4*)(yp + 12);
        float* ys = sm.b.ys;
        ys[(db + 0) * 260 + cl] = q0.x;  ys[(db + 1) * 260 + cl] = q0.y;
        ys[(db + 2) * 260 + cl] = q0.z;  ys[(db + 3) * 260 + cl] = q0.w;
        ys[(db + 4) * 260 + cl] = q1.x;  ys[(db + 5) * 260 + cl] = q1.y;
        ys[(db + 6) * 260 + cl] = q1.z;  ys[(db + 7) * 260 + cl] = q1.w;
        ys[(db + 8) * 260 + cl] = q2.x;  ys[(db + 9) * 260 + cl] = q2.y;
        ys[(db + 10) * 260 + cl] = q2.z; ys[(db + 11) * 260 + cl] = q2.w;
        ys[(db + 12) * 260 + cl] = q3.x; ys[(db + 13) * 260 + cl] = q3.y;
        ys[(db + 14) * 260 + cl] = q3.z; ys[(db + 15) * 260 + cl] = q3.w;
      }
      __syncthreads();
#pragma unroll 8
      for (int dd = 0; dd < 32; ++dd) {
        float4 y4 = *(const float4*)&sm.b.ys[dd * 260 + 4 * l];
#pragma unroll
        for (int r = 0; r < 4; ++r) {
          float xv = sm.b.xs[(w * 4 + r) * DF + 32 * h + dd];  // wave-uniform broadcast
          float d0 = xv - y4.x; acc[r][0] = fmaf(d0, d0, acc[r][0]);
          float d1 = xv - y4.y; acc[r][1] = fmaf(d1, d1, acc[r][1]);
          float d2 = xv - y4.z; acc[r][2] = fmaf(d2, d2, acc[r][2]);
          float d3 = xv - y4.w; acc[r][3] = fmaf(d3, d3, acc[r][3]);
        }
      }
    }
#pragma unroll
    for (int r = 0; r < 4; ++r) {
      vfloat4 c4 = {acc[r][0], acc[r][1], acc[r][2], acc[r][3]};
      __builtin_nontemporal_store(c4,
          (vfloat4*)(Cout + cb + (size_t)(i0 + 4 * w + r) * P + 256 * k + 4 * l));
      creg[r][4 * k + 0] = acc[r][0] * INV_EPS;
      creg[r][4 * k + 1] = acc[r][1] * INV_EPS;
      creg[r][4 * k + 2] = acc[r][2] * INV_EPS;
      creg[r][4 * k + 3] = acc[r][3] * INV_EPS;
    }
  }
  __syncthreads();  // build->comb LDS union hazard

  // ---------------- 50 Sinkhorn iterations (scaled log domain) ----------------
  float U[4];
#pragma unroll 1
  for (int it = 0; it < MAX_ITER; ++it) {
    // u-update: wave-local row LSE.  U_i = log_mu - LSE_j(V_j - Cs_ij)
    float vreg[32];
#pragma unroll
    for (int k = 0; k < 8; ++k) {
      float4 vv = *(const float4*)(Vg + n * P + 256 * k + 4 * l);
      vreg[4 * k + 0] = vv.x; vreg[4 * k + 1] = vv.y;
      vreg[4 * k + 2] = vv.z; vreg[4 * k + 3] = vv.w;
    }
#pragma unroll
    for (int r = 0; r < 4; ++r) {
      float arg[32];
      float m = -3.4e38f;
#pragma unroll
      for (int i = 0; i < 32; ++i) {
        arg[i] = vreg[i] - creg[r][i];
        m = fmaxf(m, arg[i]);
      }
#pragma unroll
      for (int off = 32; off; off >>= 1) m = fmaxf(m, __shfl_xor(m, off));
      float s = 0.f;
#pragma unroll
      for (int i = 0; i < 32; ++i) s += __expf(arg[i] - m);
#pragma unroll
      for (int off = 32; off; off >>= 1) s += __shfl_xor(s, off);
      U[r] = log_mu - (m + __logf(s));
    }
    // v-update partials over this wave's 4 rows (per column)
    float pm[32], ps[32];
#pragma unroll
    for (int i = 0; i < 32; ++i) {
      float a0 = U[0] - creg[0][i];
      float a1 = U[1] - creg[1][i];
      float a2 = U[2] - creg[2][i];
      float a3 = U[3] - creg[3][i];
      float m = fmaxf(fmaxf(a0, a1), fmaxf(a2, a3));
      pm[i] = m;
      ps[i] = __expf(a0 - m) + __expf(a1 - m) + __expf(a2 - m) + __expf(a3 - m);
    }
    // combine 8 waves -> 4 -> 1 via LDS (swizzled idx = 256k + 64e + l: conflict-free)
    if (w >= 4) {
#pragma unroll
      for (int i = 0; i < 32; ++i) {
        int idx = 256 * (i >> 2) + 64 * (i & 3) + l;
        sm.c.m[w - 4][idx] = pm[i];
        sm.c.s[w - 4][idx] = ps[i];
      }
    }
    __syncthreads();
    if (w < 4) {
#pragma unroll
      for (int i = 0; i < 32; ++i) {
        int idx = 256 * (i >> 2) + 64 * (i & 3) + l;
        float om = sm.c.m[w][idx], os = sm.c.s[w][idx];
        float M = fmaxf(pm[i], om);
        float S = ps[i] * __expf(pm[i] - M) + os * __expf(om - M);
        sm.c.m[w][idx] = M;
        sm.c.s[w][idx] = S;
      }
    }
    __syncthreads();
#pragma unroll
    for (int q = 0; q < 4; ++q) {
      int idx = t + 512 * q;  // storage order -> coalesced global write
      float m0 = sm.c.m[0][idx], m1 = sm.c.m[1][idx];
      float m2 = sm.c.m[2][idx], m3 = sm.c.m[3][idx];
      float s0 = sm.c.s[0][idx], s1 = sm.c.s[1][idx];
      float s2 = sm.c.s[2][idx], s3 = sm.c.s[3][idx];
      float M = fmaxf(fmaxf(m0, m1), fmaxf(m2, m3));
      float S = s0 * __expf(m0 - M) + s1 * __expf(m1 - M)
              + s2 * __expf(m2 - M) + s3 * __expf(m3 - M);
      part[(size_t)(n * BPB + rb) * P + idx] = make_float2(M, S);
    }
    barrier_wait(cntA, 64u * (unsigned)(it + 1), t);  // partials of batch n visible
    // reduce 64 block-partials per column -> V (block b owns cols b*32..+32)
    if (t < 32) {
      int g = b * 32 + t;
      int n2 = g >> 11, j = g & 2047;
      int pos = (j & ~255) + 64 * (j & 3) + ((j >> 2) & 63);  // un-swizzle
      float M = -3.4e38f, S = 0.f;
#pragma unroll 8
      for (int kk = 0; kk < BPB; ++kk) {
        float2 pp = part[(size_t)(n2 * BPB + kk) * P + pos];
        float Mn = fmaxf(M, pp.x);
        S = S * __expf(M - Mn) + pp.y * __expf(pp.x - Mn);
        M = Mn;
      }
      Vg[g] = log_mu - (M + __logf(S));
    }
    barrier_wait(cntB, 64u * (unsigned)(it + 1), t);  // V of batch n visible
  }

  // ---------------- epilogue: pi and cost ----------------
  float vreg2[32];
#pragma unroll
  for (int k = 0; k < 8; ++k) {
    float4 vv = *(const float4*)(Vg + n * P + 256 * k + 4 * l);
    vreg2[4 * k + 0] = vv.x; vreg2[4 * k + 1] = vv.y;
    vreg2[4 * k + 2] = vv.z; vreg2[4 * k + 3] = vv.w;
  }
  // Vg/part live inside pi region: ALL blocks must finish reading before overwrite
  barrier_wait(cntC, 256u, t);
  float csum = 0.f;
#pragma unroll
  for (int r = 0; r < 4; ++r) {
    const size_t rowb = cb + (size_t)(i0 + 4 * w + r) * P;
#pragma unroll
    for (int k = 0; k < 8; ++k) {
      vfloat4 p4;
      p4.x = __expf(U[r] + vreg2[4 * k + 0] - creg[r][4 * k + 0]);
      p4.y = __expf(U[r] + vreg2[4 * k + 1] - creg[r][4 * k + 1]);
      p4.z = __expf(U[r] + vreg2[4 * k + 2] - creg[r][4 * k + 2]);
      p4.w = __expf(U[r] + vreg2[4 * k + 3] - creg[r][4 * k + 3]);
      csum += p4.x * creg[r][4 * k + 0] + p4.y * creg[r][4 * k + 1]
            + p4.z * creg[r][4 * k + 2] + p4.w * creg[r][4 * k + 3];
      __builtin_nontemporal_store(p4, (vfloat4*)(pi + rowb + 256 * k + 4 * l));
    }
  }
  csum *= EPS;  // creg is C*INV_EPS, so sum(pi*creg)*EPS = sum(pi*C)
#pragma unroll
  for (int off = 32; off; off >>= 1) csum += __shfl_xor(csum, off);
  if (l == 0) atomicAdd(cost + n, csum);
}

// ===========================================================================
// Fallback path (round-1 kernels, known-good) in case cooperative launch fails
// ===========================================================================
__global__ __launch_bounds__(256) void build_c(const float* __restrict__ x,
                                               const float* __restrict__ y,
                                               float* __restrict__ C,
                                               float* __restrict__ CT) {
  __shared__ float xs[DF][68];
  __shared__ float ys[DF][68];
  const int n = blockIdx.z;
  const int i0 = blockIdx.y * 64, j0 = blockIdx.x * 64;
  const int t = threadIdx.x;
  const int lr = t >> 4, c4 = (t & 15) * 4;
  const size_t xb = (size_t)n * P * DF;
  for (int rr = lr; rr < 64; rr += 16) {
    float4 xv = *(const float4*)(x + xb + (size_t)(i0 + rr) * DF + c4);
    float4 yv = *(const float4*)(y + xb + (size_t)(j0 + rr) * DF + c4);
    xs[c4 + 0][rr] = xv.x; xs[c4 + 1][rr] = xv.y;
    xs[c4 + 2][rr] = xv.z; xs[c4 + 3][rr] = xv.w;
    ys[c4 + 0][rr] = yv.x; ys[c4 + 1][rr] = yv.y;
    ys[c4 + 2][rr] = yv.z; ys[c4 + 3][rr] = yv.w;
  }
  __syncthreads();
  const int ty = t >> 4, tx = t & 15;
  float acc[4][4];
#pragma unroll
  for (int e = 0; e < 4; ++e)
#pragma unroll
    for (int f = 0; f < 4; ++f) acc[e][f] = 0.f;
#pragma unroll 4
  for (int d = 0; d < DF; ++d) {
    float4 a4 = *(const float4*)&xs[d][4 * ty];
    float4 b4 = *(const float4*)&ys[d][4 * tx];
    float av[4] = {a4.x, a4.y, a4.z, a4.w};
    float bv[4] = {b4.x, b4.y, b4.z, b4.w};
#pragma unroll
    for (int e = 0; e < 4; ++e)
#pragma unroll
      for (int f = 0; f < 4; ++f) {
        float df = av[e] - bv[f];
        acc[e][f] = fmaf(df, df, acc[e][f]);
      }
  }
  const size_t cbase = (size_t)n * P * P;
#pragma unroll
  for (int e = 0; e < 4; ++e) {
    float4 v4 = make_float4(acc[e][0], acc[e][1], acc[e][2], acc[e][3]);
    *(float4*)(C + cbase + (size_t)(i0 + 4 * ty + e) * P + (j0 + 4 * tx)) = v4;
  }
#pragma unroll
  for (int f = 0; f < 4; ++f) {
    float4 v4 = make_float4(acc[0][f], acc[1][f], acc[2][f], acc[3][f]);
    *(float4*)(CT + cbase + (size_t)(j0 + 4 * tx + f) * P + (i0 + 4 * ty)) = v4;
  }
}

__global__ __launch_bounds__(256) void lse_pass(const float* __restrict__ M,
                                                const float* __restrict__ wv_,
                                                float* __restrict__ out,
                                                float log_w) {
  __shared__ float red[8];
  const int b = blockIdx.x;
  const int n = b >> 11;
  const int t = threadIdx.x;
  const float4* row = (const float4*)(M + (size_t)b * P);
  const float4* wv = (const float4*)(wv_ + (size_t)n * P);
  float4 c0 = row[t], c1 = row[t + 256];
  float4 w0 = wv[t], w1 = wv[t + 256];
  float a[8];
  a[0] = (w0.x - c0.x) * INV_EPS; a[1] = (w0.y - c0.y) * INV_EPS;
  a[2] = (w0.z - c0.z) * INV_EPS; a[3] = (w0.w - c0.w) * INV_EPS;
  a[4] = (w1.x - c1.x) * INV_EPS; a[5] = (w1.y - c1.y) * INV_EPS;
  a[6] = (w1.z - c1.z) * INV_EPS; a[7] = (w1.w - c1.w) * INV_EPS;
  float mx = a[0];
#pragma unroll
  for (int k = 1; k < 8; ++k) mx = fmaxf(mx, a[k]);
#pragma unroll
  for (int o = 32; o > 0; o >>= 1) mx = fmaxf(mx, __shfl_xor(mx, o));
  if ((t & 63) == 0) red[t >> 6] = mx;
  __syncthreads();
  mx = fmaxf(fmaxf(red[0], red[1]), fmaxf(red[2], red[3]));
  float s = 0.f;
#pragma unroll
  for (int k = 0; k < 8; ++k) s += __expf(a[k] - mx);
#pragma unroll
  for (int o = 32; o > 0; o >>= 1) s += __shfl_xor(s, o);
  if ((t & 63) == 0) red[4 + (t >> 6)] = s;
  __syncthreads();
  if (t == 0) {
    float S = red[4] + red[5] + red[6] + red[7];
    out[b] = EPS * (log_w - (mx + __logf(S)));
  }
}

__global__ __launch_bounds__(256) void final_pass(const float* __restrict__ C,
                                                  const float* __restrict__ u,
                                                  const float* __restrict__ v,
                                                  float* __restrict__ pi,
                                                  float* __restrict__ cost) {
  __shared__ float red[4];
  const int b = blockIdx.x;
  const int n = b >> 11;
  const int t = threadIdx.x;
  const float ui = u[b];
  const float4* row = (const float4*)(C + (size_t)b * P);
  const float4* vv = (const float4*)(v + (size_t)n * P);
  float4* prow = (float4*)(pi + (size_t)b * P);
  float local = 0.f;
#pragma unroll
  for (int h = 0; h < 2; ++h) {
    float4 c = row[t + 256 * h];
    float4 vw = vv[t + 256 * h];
    float4 p;
    p.x = __expf((ui + vw.x - c.x) * INV_EPS);
    p.y = __expf((ui + vw.y - c.y) * INV_EPS);
    p.z = __expf((ui + vw.z - c.z) * INV_EPS);
    p.w = __expf((ui + vw.w - c.w) * INV_EPS);
    prow[t + 256 * h] = p;
    local += p.x * c.x + p.y * c.y + p.z * c.z + p.w * c.w;
  }
#pragma unroll
  for (int o = 32; o > 0; o >>= 1) local += __shfl_xor(local, o);
  if ((t & 63) == 0) red[t >> 6] = local;
  __syncthreads();
  if (t == 0) {
    float S = red[0] + red[1] + red[2] + red[3];
    atomicAdd(cost + n, S);
  }
}

extern "C" void kernel_launch(void* const* d_in, const int* in_sizes, int n_in,
                              void* d_out, int out_size, void* d_ws, size_t ws_size,
                              hipStream_t stream) {
  const float* x = (const float*)d_in[0];
  const float* y = (const float*)d_in[1];
  float* cost = (float*)d_out;                 // 4 floats
  float* pi = cost + 4;                        // 4*2048*2048
  float* C = pi + (size_t)NB * P * P;          // 4*2048*2048
  // scratch carved out of the pi output slot (fully overwritten by epilogue):
  float2* part = (float2*)pi;                           // 4 MB of partials
  float* Vg = pi + (size_t)NB * BPB * P * 2;            // 32 KB V vector
  unsigned* cnt = (unsigned*)d_ws;                      // barrier counters

  (void)hipMemsetAsync(cost, 0, NB * sizeof(float), stream);
  (void)hipMemsetAsync(Vg, 0, NB * P * sizeof(float), stream);
  (void)hipMemsetAsync(cnt, 0, 1024, stream);

  float lmu = logf(1.0f / (float)P + 1e-8f);  // == log_nu

  void* args[] = {(void*)&x, (void*)&y, (void*)&C, (void*)&pi,
                  (void*)&cost, (void*)&part, (void*)&Vg, (void*)&cnt, (void*)&lmu};
  hipError_t err = hipLaunchCooperativeKernel((void*)sinkhorn_all, dim3(NBLK),
                                              dim3(TPB), args, 0, stream);
  if (err != hipSuccess) {
    // fallback: round-1 multi-kernel path (deterministically taken if coop fails)
    float* u = (float*)d_ws;
    float* v = u + NB * P;
    (void)hipMemsetAsync(v, 0, NB * P * sizeof(float), stream);
    float* CT = pi;
    build_c<<<dim3(32, 32, 4), 256, 0, stream>>>(x, y, C, CT);
    for (int it = 0; it < MAX_ITER; ++it) {
      lse_pass<<<NB * P, 256, 0, stream>>>(C, v, u, lmu);
      lse_pass<<<NB * P, 256, 0, stream>>>(CT, u, v, lmu);
    }
    final_pass<<<NB * P, 256, 0, stream>>>(C, u, v, pi, cost);
  }
}

// Round 5
// 1332.821 us; speedup vs baseline: 3.1941x; 1.7725x over previous
//
#include <hip/hip_runtime.h>
#include <math.h>

#define NB 4
#define P 2048
#define DF 64
#define EPS 0.1f
#define INV_EPS 10.0f
#define MAX_ITER 50
#define NBLK 256   // 1 block per CU (cooperative, co-resident)
#define TPB 512    // 8 waves
#define BPB 64     // blocks per batch
#define RPB 32     // rows per block (4 per wave)

typedef float vfloat4 __attribute__((ext_vector_type(4)));  // native vec for nt-store

struct BuildMem { float xs[RPB * DF]; float ys[32 * 260]; };  // 8KB + 33.3KB
struct CombMem  { float m[4][P]; float s[4][P]; };            // 64KB
union SMem { BuildMem b; CombMem c; };

// ---------------------------------------------------------------------------
// Agent-coherent (L2-bypassing, performed-at-L3) data movement. Relaxed
// atomics at AGENT scope emit sc0/sc1 accesses: no buffer_wbl2/buffer_inv
// cache walks anywhere in the iteration loop. Visibility protocol:
//   writer: stores -> __threadfence_block+__syncthreads (vmcnt drain; a
//           retired sc1 store is visible at L3) -> t0 stamps flag (sc1)
//   reader: poll flag (sc1) -> __syncthreads -> sc1 data loads
// ---------------------------------------------------------------------------
__device__ __forceinline__ void flag_store(unsigned* f, unsigned v) {
  __hip_atomic_store(f, v, __ATOMIC_RELAXED, __HIP_MEMORY_SCOPE_AGENT);
}
__device__ __forceinline__ unsigned flag_load(unsigned* f) {
  return __hip_atomic_load(f, __ATOMIC_RELAXED, __HIP_MEMORY_SCOPE_AGENT);
}
__device__ __forceinline__ void store_f2_agent(float2* p, float a, float b) {
  unsigned long long bits =
      ((unsigned long long)__float_as_uint(b) << 32) | __float_as_uint(a);
  __hip_atomic_store((unsigned long long*)p, bits, __ATOMIC_RELAXED,
                     __HIP_MEMORY_SCOPE_AGENT);
}
__device__ __forceinline__ float2 load_f2_agent(float2* p) {
  unsigned long long bits = __hip_atomic_load((unsigned long long*)p,
      __ATOMIC_RELAXED, __HIP_MEMORY_SCOPE_AGENT);
  return make_float2(__uint_as_float((unsigned)bits),
                     __uint_as_float((unsigned)(bits >> 32)));
}
__device__ __forceinline__ void store_f_agent(float* p, float v) {
  __hip_atomic_store(p, v, __ATOMIC_RELAXED, __HIP_MEMORY_SCOPE_AGENT);
}

// ---------------------------------------------------------------------------
// Persistent cooperative kernel: build C (+reg-resident scaled copy),
// 50 Sinkhorn iterations entirely from registers, pi/cost epilogue.
// Lane layout: wave w owns rows i0+4w..+3; lane l holds cols 256k+4l+e
// (k=0..7, e=0..3) of each of its 4 rows -> creg[4][32].
// ---------------------------------------------------------------------------
__global__ __launch_bounds__(TPB, 2) void sinkhorn_all(
    const float* __restrict__ x, const float* __restrict__ y,
    float* __restrict__ Cout, float* __restrict__ pi,
    float* __restrict__ cost, float2* __restrict__ part,
    float* __restrict__ Vg, unsigned* __restrict__ flags, float log_mu) {
  __shared__ SMem sm;
  const int t = threadIdx.x;
  const int w = t >> 6;
  const int l = t & 63;
  const int b = blockIdx.x;
  const int n = b >> 6;    // batch
  const int rb = b & 63;   // block within batch
  const int i0 = rb * RPB;
  const size_t xyb = (size_t)n * P * DF;
  const size_t cb = (size_t)n * P * P;
  unsigned* flagA = flags;        // [256] partials-ready stamp
  unsigned* flagB = flags + 256;  // [256] V-ready stamp
  unsigned* flagC = flags + 512;  // [256] epilogue rendezvous

  float creg[4][32];  // scaled cost C*INV_EPS for this lane's 4 rows x 32 cols

  // ---------------- build phase ----------------
  {
    const int rr = t >> 4, d4 = (t & 15) * 4;
    float4 xv = *(const float4*)(x + xyb + (size_t)(i0 + rr) * DF + d4);
    sm.b.xs[rr * DF + d4 + 0] = xv.x;
    sm.b.xs[rr * DF + d4 + 1] = xv.y;
    sm.b.xs[rr * DF + d4 + 2] = xv.z;
    sm.b.xs[rr * DF + d4 + 3] = xv.w;
  }
  const int cl = t >> 1;         // y-row within 256-col chunk
  const int db = (t & 1) * 16;   // d-offset within 32-d half
#pragma unroll
  for (int k = 0; k < 8; ++k) {
    float acc[4][4];
#pragma unroll
    for (int r = 0; r < 4; ++r) acc[r][0] = acc[r][1] = acc[r][2] = acc[r][3] = 0.f;
#pragma unroll
    for (int h = 0; h < 2; ++h) {
      __syncthreads();  // protect previous ys tile use (also covers xs on first pass)
      {
        const float* yp = y + xyb + (size_t)(256 * k + cl) * DF + 32 * h + db;
        float4 q0 = *(const float4*)(yp + 0);
        float4 q1 = *(const float4*)(yp + 4);
        float4 q2 = *(const float4*)(yp + 8);
        float4 q3 = *(const float4*)(yp + 12);
        float* ys = sm.b.ys;
        ys[(db + 0) * 260 + cl] = q0.x;  ys[(db + 1) * 260 + cl] = q0.y;
        ys[(db + 2) * 260 + cl] = q0.z;  ys[(db + 3) * 260 + cl] = q0.w;
        ys[(db + 4) * 260 + cl] = q1.x;  ys[(db + 5) * 260 + cl] = q1.y;
        ys[(db + 6) * 260 + cl] = q1.z;  ys[(db + 7) * 260 + cl] = q1.w;
        ys[(db + 8) * 260 + cl] = q2.x;  ys[(db + 9) * 260 + cl] = q2.y;
        ys[(db + 10) * 260 + cl] = q2.z; ys[(db + 11) * 260 + cl] = q2.w;
        ys[(db + 12) * 260 + cl] = q3.x; ys[(db + 13) * 260 + cl] = q3.y;
        ys[(db + 14) * 260 + cl] = q3.z; ys[(db + 15) * 260 + cl] = q3.w;
      }
      __syncthreads();
#pragma unroll 8
      for (int dd = 0; dd < 32; ++dd) {
        float4 y4 = *(const float4*)&sm.b.ys[dd * 260 + 4 * l];
#pragma unroll
        for (int r = 0; r < 4; ++r) {
          float xv = sm.b.xs[(w * 4 + r) * DF + 32 * h + dd];  // wave-uniform broadcast
          float d0 = xv - y4.x; acc[r][0] = fmaf(d0, d0, acc[r][0]);
          float d1 = xv - y4.y; acc[r][1] = fmaf(d1, d1, acc[r][1]);
          float d2 = xv - y4.z; acc[r][2] = fmaf(d2, d2, acc[r][2]);
          float d3 = xv - y4.w; acc[r][3] = fmaf(d3, d3, acc[r][3]);
        }
      }
    }
#pragma unroll
    for (int r = 0; r < 4; ++r) {
      vfloat4 c4 = {acc[r][0], acc[r][1], acc[r][2], acc[r][3]};
      __builtin_nontemporal_store(c4,
          (vfloat4*)(Cout + cb + (size_t)(i0 + 4 * w + r) * P + 256 * k + 4 * l));
      creg[r][4 * k + 0] = acc[r][0] * INV_EPS;
      creg[r][4 * k + 1] = acc[r][1] * INV_EPS;
      creg[r][4 * k + 2] = acc[r][2] * INV_EPS;
      creg[r][4 * k + 3] = acc[r][3] * INV_EPS;
    }
  }
  __syncthreads();  // build->comb LDS union hazard

  // ---------------- 50 Sinkhorn iterations (scaled log domain) ----------------
  float U[4];
#pragma unroll 1
  for (int it = 0; it < MAX_ITER; ++it) {
    // wait for V^(it) from this batch's 64 producers (it=0: memset zeros)
    if (t < 64) {
      unsigned* f = flagB + (n << 6) + t;
      while (flag_load(f) < (unsigned)it) __builtin_amdgcn_s_sleep(1);
    }
    __syncthreads();
    // u-update: wave-local row LSE.  U_i = log_mu - LSE_j(V_j - Cs_ij)
    float vreg[32];
    {
      float* vb = Vg + n * P;
#pragma unroll
      for (int k = 0; k < 8; ++k) {
        float2 v01 = load_f2_agent((float2*)(vb + 256 * k + 4 * l));
        float2 v23 = load_f2_agent((float2*)(vb + 256 * k + 4 * l + 2));
        vreg[4 * k + 0] = v01.x; vreg[4 * k + 1] = v01.y;
        vreg[4 * k + 2] = v23.x; vreg[4 * k + 3] = v23.y;
      }
    }
#pragma unroll
    for (int r = 0; r < 4; ++r) {
      float arg[32];
      float m = -3.4e38f;
#pragma unroll
      for (int i = 0; i < 32; ++i) {
        arg[i] = vreg[i] - creg[r][i];
        m = fmaxf(m, arg[i]);
      }
#pragma unroll
      for (int off = 32; off; off >>= 1) m = fmaxf(m, __shfl_xor(m, off));
      float s = 0.f;
#pragma unroll
      for (int i = 0; i < 32; ++i) s += __expf(arg[i] - m);
#pragma unroll
      for (int off = 32; off; off >>= 1) s += __shfl_xor(s, off);
      U[r] = log_mu - (m + __logf(s));
    }
    // v-update partials over this wave's 4 rows (per column)
    float pm[32], ps[32];
#pragma unroll
    for (int i = 0; i < 32; ++i) {
      float a0 = U[0] - creg[0][i];
      float a1 = U[1] - creg[1][i];
      float a2 = U[2] - creg[2][i];
      float a3 = U[3] - creg[3][i];
      float m = fmaxf(fmaxf(a0, a1), fmaxf(a2, a3));
      pm[i] = m;
      ps[i] = __expf(a0 - m) + __expf(a1 - m) + __expf(a2 - m) + __expf(a3 - m);
    }
    // combine 8 waves -> 4 -> 1 via LDS (swizzled idx = 256k + 64e + l: conflict-free)
    if (w >= 4) {
#pragma unroll
      for (int i = 0; i < 32; ++i) {
        int idx = 256 * (i >> 2) + 64 * (i & 3) + l;
        sm.c.m[w - 4][idx] = pm[i];
        sm.c.s[w - 4][idx] = ps[i];
      }
    }
    __syncthreads();
    if (w < 4) {
#pragma unroll
      for (int i = 0; i < 32; ++i) {
        int idx = 256 * (i >> 2) + 64 * (i & 3) + l;
        float om = sm.c.m[w][idx], os = sm.c.s[w][idx];
        float M = fmaxf(pm[i], om);
        float S = ps[i] * __expf(pm[i] - M) + os * __expf(om - M);
        sm.c.m[w][idx] = M;
        sm.c.s[w][idx] = S;
      }
    }
    __syncthreads();
#pragma unroll
    for (int q = 0; q < 4; ++q) {
      int idx = t + 512 * q;  // storage order -> coalesced L3 write
      float m0 = sm.c.m[0][idx], m1 = sm.c.m[1][idx];
      float m2 = sm.c.m[2][idx], m3 = sm.c.m[3][idx];
      float s0 = sm.c.s[0][idx], s1 = sm.c.s[1][idx];
      float s2 = sm.c.s[2][idx], s3 = sm.c.s[3][idx];
      float M = fmaxf(fmaxf(m0, m1), fmaxf(m2, m3));
      float S = s0 * __expf(m0 - M) + s1 * __expf(m1 - M)
              + s2 * __expf(m2 - M) + s3 * __expf(m3 - M);
      store_f2_agent(&part[(size_t)((n << 6) + rb) * P + idx], M, S);
    }
    __threadfence_block();  // s_waitcnt only: sc1 stores retired => visible at L3
    __syncthreads();
    if (t == 0) flag_store(&flagA[b], (unsigned)(it + 1));

    // wait for all 64 producers' partials, then parallel column reduce:
    // 256 lanes = 32 cols x 8 groups; each lane merges 8 partials, then
    // 3-step shuffle butterfly combines the 8 groups.
    if (t < 64) {
      unsigned* f = flagA + (n << 6) + t;
      while (flag_load(f) < (unsigned)(it + 1)) __builtin_amdgcn_s_sleep(1);
    }
    __syncthreads();
    if (t < 256) {
      const int col = t >> 3;
      const int sub = t & 7;
      const int j = ((b & 63) << 5) + col;  // column within batch
      const int pos = (j & ~255) + 64 * (j & 3) + ((j >> 2) & 63);  // un-swizzle
      float M = -3.4e38f, S = 0.f;
#pragma unroll
      for (int q = 0; q < 8; ++q) {
        int kk = sub * 8 + q;
        float2 pp = load_f2_agent(&part[(size_t)((n << 6) + kk) * P + pos]);
        float Mn = fmaxf(M, pp.x);
        S = S * __expf(M - Mn) + pp.y * __expf(pp.x - Mn);
        M = Mn;
      }
#pragma unroll
      for (int off = 1; off < 8; off <<= 1) {
        float Mo = __shfl_xor(M, off);
        float So = __shfl_xor(S, off);
        float Mn = fmaxf(M, Mo);
        S = S * __expf(M - Mn) + So * __expf(Mo - Mn);
        M = Mn;
      }
      if (sub == 0) store_f_agent(&Vg[n * P + j], log_mu - (M + __logf(S)));
    }
    __threadfence_block();
    __syncthreads();
    if (t == 0) flag_store(&flagB[b], (unsigned)(it + 1));
  }

  // ---------------- epilogue: pi and cost ----------------
  if (t < 64) {  // final V^(50)
    unsigned* f = flagB + (n << 6) + t;
    while (flag_load(f) < (unsigned)MAX_ITER) __builtin_amdgcn_s_sleep(1);
  }
  __syncthreads();
  float vreg2[32];
  {
    float* vb = Vg + n * P;
#pragma unroll
    for (int k = 0; k < 8; ++k) {
      float2 v01 = load_f2_agent((float2*)(vb + 256 * k + 4 * l));
      float2 v23 = load_f2_agent((float2*)(vb + 256 * k + 4 * l + 2));
      vreg2[4 * k + 0] = v01.x; vreg2[4 * k + 1] = v01.y;
      vreg2[4 * k + 2] = v23.x; vreg2[4 * k + 3] = v23.y;
    }
  }
  // part/Vg live inside the pi region: global rendezvous before overwrite
  __threadfence_block();
  __syncthreads();
  if (t == 0) flag_store(&flagC[b], 1u);
  if (t < 256) {
    unsigned* f = flagC + t;
    while (flag_load(f) < 1u) __builtin_amdgcn_s_sleep(1);
  }
  __syncthreads();
  float csum = 0.f;
#pragma unroll
  for (int r = 0; r < 4; ++r) {
    const size_t rowb = cb + (size_t)(i0 + 4 * w + r) * P;
#pragma unroll
    for (int k = 0; k < 8; ++k) {
      vfloat4 p4;
      p4.x = __expf(U[r] + vreg2[4 * k + 0] - creg[r][4 * k + 0]);
      p4.y = __expf(U[r] + vreg2[4 * k + 1] - creg[r][4 * k + 1]);
      p4.z = __expf(U[r] + vreg2[4 * k + 2] - creg[r][4 * k + 2]);
      p4.w = __expf(U[r] + vreg2[4 * k + 3] - creg[r][4 * k + 3]);
      csum += p4.x * creg[r][4 * k + 0] + p4.y * creg[r][4 * k + 1]
            + p4.z * creg[r][4 * k + 2] + p4.w * creg[r][4 * k + 3];
      __builtin_nontemporal_store(p4, (vfloat4*)(pi + rowb + 256 * k + 4 * l));
    }
  }
  csum *= EPS;  // creg is C*INV_EPS, so sum(pi*creg)*EPS = sum(pi*C)
#pragma unroll
  for (int off = 32; off; off >>= 1) csum += __shfl_xor(csum, off);
  if (l == 0) atomicAdd(cost + n, csum);
}

// ===========================================================================
// Fallback path (round-1 kernels, known-good) in case cooperative launch fails
// ===========================================================================
__global__ __launch_bounds__(256) void build_c(const float* __restrict__ x,
                                               const float* __restrict__ y,
                                               float* __restrict__ C,
                                               float* __restrict__ CT) {
  __shared__ float xs[DF][68];
  __shared__ float ys[DF][68];
  const int n = blockIdx.z;
  const int i0 = blockIdx.y * 64, j0 = blockIdx.x * 64;
  const int t = threadIdx.x;
  const int lr = t >> 4, c4 = (t & 15) * 4;
  const size_t xb = (size_t)n * P * DF;
  for (int rr = lr; rr < 64; rr += 16) {
    float4 xv = *(const float4*)(x + xb + (size_t)(i0 + rr) * DF + c4);
    float4 yv = *(const float4*)(y + xb + (size_t)(j0 + rr) * DF + c4);
    xs[c4 + 0][rr] = xv.x; xs[c4 + 1][rr] = xv.y;
    xs[c4 + 2][rr] = xv.z; xs[c4 + 3][rr] = xv.w;
    ys[c4 + 0][rr] = yv.x; ys[c4 + 1][rr] = yv.y;
    ys[c4 + 2][rr] = yv.z; ys[c4 + 3][rr] = yv.w;
  }
  __syncthreads();
  const int ty = t >> 4, tx = t & 15;
  float acc[4][4];
#pragma unroll
  for (int e = 0; e < 4; ++e)
#pragma unroll
    for (int f = 0; f < 4; ++f) acc[e][f] = 0.f;
#pragma unroll 4
  for (int d = 0; d < DF; ++d) {
    float4 a4 = *(const float4*)&xs[d][4 * ty];
    float4 b4 = *(const float4*)&ys[d][4 * tx];
    float av[4] = {a4.x, a4.y, a4.z, a4.w};
    float bv[4] = {b4.x, b4.y, b4.z, b4.w};
#pragma unroll
    for (int e = 0; e < 4; ++e)
#pragma unroll
      for (int f = 0; f < 4; ++f) {
        float df = av[e] - bv[f];
        acc[e][f] = fmaf(df, df, acc[e][f]);
      }
  }
  const size_t cbase = (size_t)n * P * P;
#pragma unroll
  for (int e = 0; e < 4; ++e) {
    float4 v4 = make_float4(acc[e][0], acc[e][1], acc[e][2], acc[e][3]);
    *(float4*)(C + cbase + (size_t)(i0 + 4 * ty + e) * P + (j0 + 4 * tx)) = v4;
  }
#pragma unroll
  for (int f = 0; f < 4; ++f) {
    float4 v4 = make_float4(acc[0][f], acc[1][f], acc[2][f], acc[3][f]);
    *(float4*)(CT + cbase + (size_t)(j0 + 4 * tx + f) * P + (i0 + 4 * ty)) = v4;
  }
}

__global__ __launch_bounds__(256) void lse_pass(const float* __restrict__ M,
                                                const float* __restrict__ wv_,
                                                float* __restrict__ out,
                                                float log_w) {
  __shared__ float red[8];
  const int b = blockIdx.x;
  const int n = b >> 11;
  const int t = threadIdx.x;
  const float4* row = (const float4*)(M + (size_t)b * P);
  const float4* wv = (const float4*)(wv_ + (size_t)n * P);
  float4 c0 = row[t], c1 = row[t + 256];
  float4 w0 = wv[t], w1 = wv[t + 256];
  float a[8];
  a[0] = (w0.x - c0.x) * INV_EPS; a[1] = (w0.y - c0.y) * INV_EPS;
  a[2] = (w0.z - c0.z) * INV_EPS; a[3] = (w0.w - c0.w) * INV_EPS;
  a[4] = (w1.x - c1.x) * INV_EPS; a[5] = (w1.y - c1.y) * INV_EPS;
  a[6] = (w1.z - c1.z) * INV_EPS; a[7] = (w1.w - c1.w) * INV_EPS;
  float mx = a[0];
#pragma unroll
  for (int k = 1; k < 8; ++k) mx = fmaxf(mx, a[k]);
#pragma unroll
  for (int o = 32; o > 0; o >>= 1) mx = fmaxf(mx, __shfl_xor(mx, o));
  if ((t & 63) == 0) red[t >> 6] = mx;
  __syncthreads();
  mx = fmaxf(fmaxf(red[0], red[1]), fmaxf(red[2], red[3]));
  float s = 0.f;
#pragma unroll
  for (int k = 0; k < 8; ++k) s += __expf(a[k] - mx);
#pragma unroll
  for (int o = 32; o > 0; o >>= 1) s += __shfl_xor(s, o);
  if ((t & 63) == 0) red[4 + (t >> 6)] = s;
  __syncthreads();
  if (t == 0) {
    float S = red[4] + red[5] + red[6] + red[7];
    out[b] = EPS * (log_w - (mx + __logf(S)));
  }
}

__global__ __launch_bounds__(256) void final_pass(const float* __restrict__ C,
                                                  const float* __restrict__ u,
                                                  const float* __restrict__ v,
                                                  float* __restrict__ pi,
                                                  float* __restrict__ cost) {
  __shared__ float red[4];
  const int b = blockIdx.x;
  const int n = b >> 11;
  const int t = threadIdx.x;
  const float ui = u[b];
  const float4* row = (const float4*)(C + (size_t)b * P);
  const float4* vv = (const float4*)(v + (size_t)n * P);
  float4* prow = (float4*)(pi + (size_t)b * P);
  float local = 0.f;
#pragma unroll
  for (int h = 0; h < 2; ++h) {
    float4 c = row[t + 256 * h];
    float4 vw = vv[t + 256 * h];
    float4 p;
    p.x = __expf((ui + vw.x - c.x) * INV_EPS);
    p.y = __expf((ui + vw.y - c.y) * INV_EPS);
    p.z = __expf((ui + vw.z - c.z) * INV_EPS);
    p.w = __expf((ui + vw.w - c.w) * INV_EPS);
    prow[t + 256 * h] = p;
    local += p.x * c.x + p.y * c.y + p.z * c.z + p.w * c.w;
  }
#pragma unroll
  for (int o = 32; o > 0; o >>= 1) local += __shfl_xor(local, o);
  if ((t & 63) == 0) red[t >> 6] = local;
  __syncthreads();
  if (t == 0) {
    float S = red[0] + red[1] + red[2] + red[3];
    atomicAdd(cost + n, S);
  }
}

extern "C" void kernel_launch(void* const* d_in, const int* in_sizes, int n_in,
                              void* d_out, int out_size, void* d_ws, size_t ws_size,
                              hipStream_t stream) {
  const float* x = (const float*)d_in[0];
  const float* y = (const float*)d_in[1];
  float* cost = (float*)d_out;                 // 4 floats
  float* pi = cost + 4;                        // 4*2048*2048
  float* C = pi + (size_t)NB * P * P;          // 4*2048*2048
  // scratch carved out of the pi output slot (fully overwritten by epilogue):
  float2* part = (float2*)pi;                           // 4 MB of partials
  float* Vg = pi + (size_t)NB * BPB * P * 2;            // 32 KB V vector
  unsigned* flags = (unsigned*)d_ws;                    // stamped flags

  (void)hipMemsetAsync(cost, 0, NB * sizeof(float), stream);
  (void)hipMemsetAsync(Vg, 0, NB * P * sizeof(float), stream);
  (void)hipMemsetAsync(flags, 0, 4096, stream);

  float lmu = logf(1.0f / (float)P + 1e-8f);  // == log_nu

  void* args[] = {(void*)&x, (void*)&y, (void*)&C, (void*)&pi,
                  (void*)&cost, (void*)&part, (void*)&Vg, (void*)&flags,
                  (void*)&lmu};
  hipError_t err = hipLaunchCooperativeKernel((void*)sinkhorn_all, dim3(NBLK),
                                              dim3(TPB), args, 0, stream);
  if (err != hipSuccess) {
    // fallback: round-1 multi-kernel path (deterministically taken if coop fails)
    float* u = (float*)d_ws;
    float* v = u + NB * P;
    (void)hipMemsetAsync(v, 0, NB * P * sizeof(float), stream);
    float* CT = pi;
    build_c<<<dim3(32, 32, 4), 256, 0, stream>>>(x, y, C, CT);
    for (int it = 0; it < MAX_ITER; ++it) {
      lse_pass<<<NB * P, 256, 0, stream>>>(C, v, u, lmu);
      lse_pass<<<NB * P, 256, 0, stream>>>(CT, u, v, lmu);
    }
    final_pass<<<NB * P, 256, 0, stream>>>(C, u, v, pi, cost);
  }
}